// Round 5
// baseline (513.378 us; speedup 1.0000x reference)
//
#include <hip/hip_runtime.h>
#include <hip/hip_bf16.h>
#include <stdint.h>

// Problem constants
#define BATCH   4096
#define CONTENT 200
#define EMBED   128
#define HIDDEN  1024
#define KDIM    (CONTENT*EMBED)   // 25600
#define SPLITK  4                 // 4 chunks x 100 K-tiles(64) = 50 tokens each

typedef __bf16 bf16_t;
typedef __bf16 bf16x8 __attribute__((ext_vector_type(8)));
typedef float  f32x4  __attribute__((ext_vector_type(4)));

// Workspace layout (bytes)
#define WS_EMBT  0ull                      // emb bf16 [50000][128] = 12,800,000 B
#define WS_W1    12800000ull               // w1 bf16 [1024][25600] = 52,428,800 B
#define WS_HP    65228800ull               // 4 x f32 [4096][1024]  = 67,108,864 B
#define HP_STRIDE 4194304ull               // floats per partial buffer

__device__ int g_cnt[16];                  // split-K arrival counters (reset by k_prep)

__device__ __forceinline__ void gload_lds16(const void* g, void* l) {
  __builtin_amdgcn_global_load_lds(
      (const __attribute__((address_space(1))) uint32_t*)g,
      (__attribute__((address_space(3))) uint32_t*)l, 16, 0, 0);
}

// ---------------- Kernel 1: prep — zero counters, cast emb (zero row 0) + cast w1 ----------------
__global__ __launch_bounds__(256) void k_prep(const float* __restrict__ emb,
                                              const float* __restrict__ w1,
                                              bf16_t* __restrict__ embT,
                                              bf16_t* __restrict__ w1T) {
  if (blockIdx.x == 0 && threadIdx.x < 16) g_cnt[threadIdx.x] = 0;
  const int TOT = 4076800;                 // 800000 emb units + 3276800 w1 units (of 8 elems)
  int stride = gridDim.x * 256;
  for (int u = blockIdx.x * 256 + threadIdx.x; u < TOT; u += stride) {
    if (u < 800000) {
      const float4* s = (const float4*)(emb + (size_t)u * 8);
      float4 f0 = s[0], f1 = s[1];
      float sc = (u >> 4) == 0 ? 0.0f : 1.0f;   // padding_idx = 0
      bf16x8 r;
      r[0]=(bf16_t)(f0.x*sc); r[1]=(bf16_t)(f0.y*sc); r[2]=(bf16_t)(f0.z*sc); r[3]=(bf16_t)(f0.w*sc);
      r[4]=(bf16_t)(f1.x*sc); r[5]=(bf16_t)(f1.y*sc); r[6]=(bf16_t)(f1.z*sc); r[7]=(bf16_t)(f1.w*sc);
      *(bf16x8*)(embT + (size_t)u * 8) = r;
    } else {
      long long v = u - 800000;
      const float4* s = (const float4*)(w1 + v * 8);
      float4 f0 = s[0], f1 = s[1];
      bf16x8 r;
      r[0]=(bf16_t)f0.x; r[1]=(bf16_t)f0.y; r[2]=(bf16_t)f0.z; r[3]=(bf16_t)f0.w;
      r[4]=(bf16_t)f1.x; r[5]=(bf16_t)f1.y; r[6]=(bf16_t)f1.z; r[7]=(bf16_t)f1.w;
      *(bf16x8*)(w1T + v * 8) = r;
    }
  }
}

// ---------------- Kernel 2: fused gather-GEMM + split-K reduce epilogue ----------------
// 256x256 tile, BK=64, 8 waves, 8-phase counted-vmcnt schedule (verified round 4).
// Round-5 change: fragment-carrying phases — each K-tile reads each LDS fragment ONCE:
//   P1: read af0+bf0 (12 ds_read_b128), mfma af0 x bf0  (acc[0..3][0..1])
//   P2: read bf1      (4),              mfma af0 x bf1  (acc[0..3][2..3])
//   P3: read af1      (8),              mfma af1 x bf1  (acc[4..7][2..3])
//   P4: read none,                      mfma af1 x bf0  (acc[4..7][0..1])
// Stage slots + vmcnt(4) at p3/p7 unchanged from round 4 (all RAW/WAR re-proven).
__global__ __launch_bounds__(512, 2) void k_gemm(const int* __restrict__ x,
                                                 const bf16_t* __restrict__ embT,
                                                 const bf16_t* __restrict__ W,
                                                 float* __restrict__ hp,
                                                 const float* __restrict__ b1,
                                                 const float* __restrict__ w2,
                                                 const float* __restrict__ b2,
                                                 float* __restrict__ out) {
  __shared__ char smem[131072];
  const int tid = threadIdx.x;
  const int wid = tid >> 6, l = tid & 63;
  // bijective XCD swizzle: 256 blocks, 8 XCDs, 32 consecutive origs per XCD
  const int orig = (blockIdx.x & 7) * 32 + (blockIdx.x >> 3);
  const int m0 = (orig & 15) * 256;
  const int n0 = ((orig >> 4) & 3) * 256;
  const int chunk = orig >> 6;
  const int cb100 = chunk * 100;          // chunk K-tile base
  const int T0 = chunk * 50;              // chunk token base

  // ---- staging constants (verified r4)
  const int sg16 = ((l & 7) ^ (l >> 3)) * 16;
  const char* embB = (const char*)embT;
  const char* Wb = (const char*)W;
  const int wq = wid >> 2, wm = wid & 3;
  size_t brow[2];
  #pragma unroll
  for (int rd = 0; rd < 2; ++rd)
    brow[rd] = (size_t)(n0 + rd*128 + wq*64 + wm*8 + (l>>3)) * (size_t)(KDIM*2) + sg16;
  int xrow[4];
  #pragma unroll
  for (int f = 0; f < 4; ++f)
    xrow[f] = (m0 + (f>>1)*128 + (f&1)*64 + (tid>>3)) * CONTENT;

  // ---- fragment constants (verified r4)
  const int wr = wq, wc = wm;
  const int lane_r = l & 15, g = l >> 4;
  const int aoff = wr*16384 + lane_r*128;
  const int boff = 32768 + wc*8192 + lane_r*128;
  const int s0 = ((0*4 + g) ^ (lane_r & 7)) * 16;
  const int s1 = ((1*4 + g) ^ (lane_r & 7)) * 16;

#define ISSUE_A(BUF, H, XA, KOFF)                                             \
  { gload_lds16(embB + (size_t)XA[0*2+(H)]*256 + (KOFF) + sg16,               \
                smem + (BUF) + 0*16384 + (H)*8192 + wid*1024);                \
    gload_lds16(embB + (size_t)XA[1*2+(H)]*256 + (KOFF) + sg16,               \
                smem + (BUF) + 1*16384 + (H)*8192 + wid*1024); }
#define ISSUE_B(BUF, H, LT)                                                   \
  { const int lt_ = (LT) > 99 ? 99 : (LT);                                    \
    const size_t ko_ = (size_t)(cb100 + lt_) * 128 + (H)*1638400u;            \
    gload_lds16(Wb + brow[0] + ko_,                                           \
                smem + (BUF) + 32768 + 0*16384 + wq*8192 + (H)*4096 + wm*1024); \
    gload_lds16(Wb + brow[1] + ko_,                                           \
                smem + (BUF) + 32768 + 1*16384 + wq*8192 + (H)*4096 + wm*1024); }

#define MM8(AF, BF, IB, JB)                                                   \
  _Pragma("unroll") for (int ii = 0; ii < 4; ++ii)                            \
    _Pragma("unroll") for (int jj = 0; jj < 2; ++jj) {                        \
      acc[(IB)+ii][(JB)+jj] = __builtin_amdgcn_mfma_f32_16x16x32_bf16(        \
          AF[ii][0], BF[jj][0], acc[(IB)+ii][(JB)+jj], 0, 0, 0);              \
      acc[(IB)+ii][(JB)+jj] = __builtin_amdgcn_mfma_f32_16x16x32_bf16(        \
          AF[ii][1], BF[jj][1], acc[(IB)+ii][(JB)+jj], 0, 0, 0);              \
    }

#define RD_AF(DST, CB, H)                                                     \
  _Pragma("unroll") for (int ii = 0; ii < 4; ++ii) {                          \
    DST[ii][0] = *(const bf16x8*)(smem + (CB) + aoff + (H)*8192 + ii*2048 + s0); \
    DST[ii][1] = *(const bf16x8*)(smem + (CB) + aoff + (H)*8192 + ii*2048 + s1); \
  }
#define RD_BF(DST, CB, H)                                                     \
  _Pragma("unroll") for (int jj = 0; jj < 2; ++jj) {                          \
    DST[jj][0] = *(const bf16x8*)(smem + (CB) + boff + (H)*4096 + jj*2048 + s0); \
    DST[jj][1] = *(const bf16x8*)(smem + (CB) + boff + (H)*4096 + jj*2048 + s1); \
  }

#define BARW  __builtin_amdgcn_s_barrier();                                   \
              asm volatile("s_waitcnt lgkmcnt(0)" ::: "memory");

#define TILE(CB, ST1, ST2, ST3, ST4, TAIL4)                                   \
  { RD_AF(af0, CB, 0) RD_BF(bf0, CB, 0)                                       \
    ST1                                                                       \
    BARW                                                                      \
    __builtin_amdgcn_s_setprio(1); MM8(af0, bf0, 0, 0)                        \
    __builtin_amdgcn_s_setprio(0);                                            \
    __builtin_amdgcn_s_barrier();                                             \
    RD_BF(bf1, CB, 1)                                                         \
    ST2                                                                       \
    BARW                                                                      \
    __builtin_amdgcn_s_setprio(1); MM8(af0, bf1, 0, 2)                        \
    __builtin_amdgcn_s_setprio(0);                                            \
    __builtin_amdgcn_s_barrier();                                             \
    RD_AF(af1, CB, 1)                                                         \
    ST3                                                                       \
    BARW                                                                      \
    __builtin_amdgcn_s_setprio(1); MM8(af1, bf1, 4, 2)                        \
    __builtin_amdgcn_s_setprio(0);                                            \
    __builtin_amdgcn_s_barrier();                                             \
    ST4                                                                       \
    __builtin_amdgcn_s_barrier();                                             \
    __builtin_amdgcn_s_setprio(1); MM8(af1, bf0, 4, 0)                        \
    __builtin_amdgcn_s_setprio(0);                                            \
    TAIL4                                                                     \
    __builtin_amdgcn_s_barrier(); }

  f32x4 acc[8][4];
  #pragma unroll
  for (int i = 0; i < 8; ++i)
    #pragma unroll
    for (int j = 0; j < 4; ++j)
      acc[i][j] = (f32x4){0.f, 0.f, 0.f, 0.f};

  bf16x8 af0[4][2], af1[4][2], bf0[2][2], bf1[2][2];

  // ---- prologue: tile0 (A0,A1,B0,B1)->buf0 + tile1 (A0,B0)->buf1; keep tile1 in flight
  int xcur[4], xnxt[4];
  #pragma unroll
  for (int f = 0; f < 4; ++f) xcur[f] = x[xrow[f] + T0];
  #pragma unroll
  for (int f = 0; f < 4; ++f) xnxt[f] = x[xrow[f] + T0 + 1];
  ISSUE_A(0, 0, xcur, 0)
  ISSUE_A(0, 1, xcur, 0)
  ISSUE_B(0, 0, 0)
  ISSUE_B(0, 1, 0)
  ISSUE_A(65536, 0, xcur, 128)
  ISSUE_B(65536, 0, 1)
  asm volatile("s_waitcnt vmcnt(4)" ::: "memory");
  __builtin_amdgcn_s_barrier();

  for (int j = 0; j < 50; ++j) {
    int tnew = T0 + j + 2; if (tnew > CONTENT - 1) tnew = CONTENT - 1;
    int xnew[4];
    #pragma unroll
    for (int f = 0; f < 4; ++f) xnew[f] = x[xrow[f] + tnew];

    // even tile 2j in buf0; stage slots p0-p3
    TILE(0,
         { ISSUE_A(65536, 1, xcur, 128); },
         { ISSUE_B(65536, 1, 2*j+1); },
         { ISSUE_A(0, 0, xnxt, 0); },
         { ISSUE_B(0, 0, 2*j+2); },
         { asm volatile("s_waitcnt vmcnt(4)" ::: "memory"); })
    // odd tile 2j+1 in buf1; stage slots p4-p7
    TILE(65536,
         { ISSUE_A(0, 1, xnxt, 0); },
         { ISSUE_B(0, 1, 2*j+2); },
         { ISSUE_A(65536, 0, xnxt, 128); },
         { ISSUE_B(65536, 0, 2*j+3); },
         { asm volatile("s_waitcnt vmcnt(4)" ::: "memory"); })

    #pragma unroll
    for (int f = 0; f < 4; ++f) { xcur[f] = xnxt[f]; xnxt[f] = xnew[f]; }
  }
#undef TILE
#undef BARW
#undef RD_AF
#undef RD_BF
#undef MM8
#undef ISSUE_A
#undef ISSUE_B

  asm volatile("s_waitcnt vmcnt(0)" ::: "memory");

  // ---- partial store: C/D layout col = lane&15, row = (lane>>4)*4 + reg [HW-verified]
  float* hout = hp + (size_t)chunk * HP_STRIDE;
  const int colBase = n0 + wc * 64 + lane_r;
  const int rowBase = m0 + wr * 128 + (l >> 4) * 4;
  #pragma unroll
  for (int i = 0; i < 8; ++i)
    #pragma unroll
    for (int jj = 0; jj < 4; ++jj)
      #pragma unroll
      for (int r = 0; r < 4; ++r)
        hout[(size_t)(rowBase + i * 16 + r) * HIDDEN + colBase + jj * 16] = acc[i][jj][r];

  // ---- device-scope handshake: all 16 blocks of this m-panel done?
  __threadfence();                        // agent release: flush L2 so L3 has our partials
  const int m0i = orig & 15;
  __syncthreads();
  if (tid == 0) {
    atomicAdd(&g_cnt[m0i], 1);
    while (atomicAdd(&g_cnt[m0i], 0) < 16) __builtin_amdgcn_s_sleep(8);
  }
  __syncthreads();
  __threadfence();

  // ---- fused reduce: this block handles 16 rows (rank = orig>>4)
  const int rank = orig >> 4;             // 0..15
  const int mrow = m0 + rank * 16 + (tid >> 5);
  const int c0 = (tid & 31) * 32;
  const float* h0 = hp + (size_t)mrow * HIDDEN + c0;
  float l0 = 0.f, l1 = 0.f;
  #pragma unroll
  for (int q = 0; q < 8; ++q) {
    float4 p0 = *(const float4*)(h0 + q * 4);
    float4 p1 = *(const float4*)(h0 + HP_STRIDE + q * 4);
    float4 p2 = *(const float4*)(h0 + 2 * HP_STRIDE + q * 4);
    float4 p3 = *(const float4*)(h0 + 3 * HP_STRIDE + q * 4);
    float4 bb = *(const float4*)(b1 + c0 + q * 4);
    float4 wa = *(const float4*)(w2 + c0 + q * 4);
    float4 wb = *(const float4*)(w2 + HIDDEN + c0 + q * 4);
    float h;
    h = p0.x + p1.x + p2.x + p3.x + bb.x; h = fmaxf(h, 0.f); l0 += h * wa.x; l1 += h * wb.x;
    h = p0.y + p1.y + p2.y + p3.y + bb.y; h = fmaxf(h, 0.f); l0 += h * wa.y; l1 += h * wb.y;
    h = p0.z + p1.z + p2.z + p3.z + bb.z; h = fmaxf(h, 0.f); l0 += h * wa.z; l1 += h * wb.z;
    h = p0.w + p1.w + p2.w + p3.w + bb.w; h = fmaxf(h, 0.f); l0 += h * wa.w; l1 += h * wb.w;
  }
  #pragma unroll
  for (int off = 16; off > 0; off >>= 1) {
    l0 += __shfl_xor(l0, off, 64);
    l1 += __shfl_xor(l1, off, 64);
  }
  if ((tid & 31) == 0) {
    float z0 = l0 + b2[0], z1 = l1 + b2[1];
    float mx = fmaxf(z0, z1);
    float e0 = expf(z0 - mx), e1 = expf(z1 - mx);
    float s = 1.f / (e0 + e1);
    out[2 * mrow]     = e0 * s;
    out[2 * mrow + 1] = e1 * s;
  }
}

extern "C" void kernel_launch(void* const* d_in, const int* in_sizes, int n_in,
                              void* d_out, int out_size, void* d_ws, size_t ws_size,
                              hipStream_t stream) {
  (void)in_sizes; (void)n_in; (void)out_size; (void)ws_size;
  const int*   x   = (const int*)d_in[0];
  const float* emb = (const float*)d_in[1];
  const float* w1  = (const float*)d_in[2];
  const float* b1  = (const float*)d_in[3];
  const float* w2  = (const float*)d_in[4];
  const float* b2  = (const float*)d_in[5];
  float* out = (float*)d_out;
  char* ws = (char*)d_ws;
  bf16_t* embT = (bf16_t*)(ws + WS_EMBT);
  bf16_t* Wbf  = (bf16_t*)(ws + WS_W1);
  float*  hp   = (float*)(ws + WS_HP);

  hipLaunchKernelGGL(k_prep, dim3(2048), dim3(256), 0, stream, emb, w1, embT, Wbf);
  hipLaunchKernelGGL(k_gemm, dim3(256), dim3(512), 0, stream,
                     x, embT, Wbf, hp, b1, w2, b2, out);
}

// Round 7
// 378.240 us; speedup vs baseline: 1.3573x; 1.3573x over previous
//
#include <hip/hip_runtime.h>
#include <hip/hip_bf16.h>
#include <stdint.h>

// Problem constants
#define BATCH   4096
#define CONTENT 200
#define EMBED   128
#define HIDDEN  1024
#define KDIM    (CONTENT*EMBED)   // 25600
#define SPLITK  4                 // 4 chunks x 100 K-tiles(64) = 50 tokens each

typedef __bf16 bf16_t;
typedef __bf16 bf16x8 __attribute__((ext_vector_type(8)));
typedef float  f32x4  __attribute__((ext_vector_type(4)));

// Workspace layout (bytes)
#define WS_EMBT  0ull                      // emb bf16 [50000][128] = 12,800,000 B
#define WS_W1    12800000ull               // w1 bf16 [1024][25600] = 52,428,800 B
#define WS_HP    65228800ull               // 4 x f32 [4096][1024]  = 67,108,864 B
#define HP_STRIDE 4194304ull               // floats per partial buffer

__device__ __forceinline__ void gload_lds16(const void* g, void* l) {
  __builtin_amdgcn_global_load_lds(
      (const __attribute__((address_space(1))) uint32_t*)g,
      (__attribute__((address_space(3))) uint32_t*)l, 16, 0, 0);
}

// ---------------- Kernel 1: prep — cast emb (zero row 0) + cast w1, uniform stride ----------------
__global__ __launch_bounds__(256) void k_prep(const float* __restrict__ emb,
                                              const float* __restrict__ w1,
                                              bf16_t* __restrict__ embT,
                                              bf16_t* __restrict__ w1T) {
  const int TOT = 4076800;                 // 800000 emb units + 3276800 w1 units (of 8 elems)
  int stride = gridDim.x * 256;
  for (int u = blockIdx.x * 256 + threadIdx.x; u < TOT; u += stride) {
    if (u < 800000) {
      const float4* s = (const float4*)(emb + (size_t)u * 8);
      float4 f0 = s[0], f1 = s[1];
      float sc = (u >> 4) == 0 ? 0.0f : 1.0f;   // padding_idx = 0
      bf16x8 r;
      r[0]=(bf16_t)(f0.x*sc); r[1]=(bf16_t)(f0.y*sc); r[2]=(bf16_t)(f0.z*sc); r[3]=(bf16_t)(f0.w*sc);
      r[4]=(bf16_t)(f1.x*sc); r[5]=(bf16_t)(f1.y*sc); r[6]=(bf16_t)(f1.z*sc); r[7]=(bf16_t)(f1.w*sc);
      *(bf16x8*)(embT + (size_t)u * 8) = r;
    } else {
      long long v = u - 800000;
      const float4* s = (const float4*)(w1 + v * 8);
      float4 f0 = s[0], f1 = s[1];
      bf16x8 r;
      r[0]=(bf16_t)f0.x; r[1]=(bf16_t)f0.y; r[2]=(bf16_t)f0.z; r[3]=(bf16_t)f0.w;
      r[4]=(bf16_t)f1.x; r[5]=(bf16_t)f1.y; r[6]=(bf16_t)f1.z; r[7]=(bf16_t)f1.w;
      *(bf16x8*)(w1T + v * 8) = r;
    }
  }
}

// ---------------- Kernel 2: fused gather-GEMM, 256x256 8-phase counted-vmcnt ----------------
// Round-4 skeleton (verified 224us): stage slots p0-p3/p4-p7, vmcnt(4) at p3/p7.
// Round-6 change (ONLY change vs r4): dedup-lite LDS reads. Quadrant order per K-tile
// (0,0)(0,1)(1,0)(1,1); af half read ONCE (lives across exactly one barrier, 32 VGPR),
// bf half RE-READ each phase (4 reads). 32 ds_read_b128/tile/wave vs r4's 48.
// WAR/RAW re-proven: af0 (read P1/P2) overwritten by ST3 -- >=1 barrier after last read;
// bf0 re-read P3 completes (lgkm+barrier) before ST4 overwrites; drain sets unchanged.
__global__ __launch_bounds__(512, 2) void k_gemm(const int* __restrict__ x,
                                                 const bf16_t* __restrict__ embT,
                                                 const bf16_t* __restrict__ W,
                                                 float* __restrict__ hp) {
  __shared__ char smem[131072];
  const int tid = threadIdx.x;
  const int wid = tid >> 6, l = tid & 63;
  // bijective XCD swizzle: 256 blocks, 8 XCDs, 32 consecutive origs per XCD
  const int orig = (blockIdx.x & 7) * 32 + (blockIdx.x >> 3);
  const int m0 = (orig & 15) * 256;
  const int n0 = ((orig >> 4) & 3) * 256;
  const int chunk = orig >> 6;
  const int cb100 = chunk * 100;          // chunk K-tile base
  const int T0 = chunk * 50;              // chunk token base

  // ---- staging constants (verified r4)
  const int sg16 = ((l & 7) ^ (l >> 3)) * 16;
  const char* embB = (const char*)embT;
  const char* Wb = (const char*)W;
  const int wq = wid >> 2, wm = wid & 3;
  size_t brow[2];
  #pragma unroll
  for (int rd = 0; rd < 2; ++rd)
    brow[rd] = (size_t)(n0 + rd*128 + wq*64 + wm*8 + (l>>3)) * (size_t)(KDIM*2) + sg16;
  int xrow[4];
  #pragma unroll
  for (int f = 0; f < 4; ++f)
    xrow[f] = (m0 + (f>>1)*128 + (f&1)*64 + (tid>>3)) * CONTENT;

  // ---- fragment constants (verified r4)
  const int wr = wq, wc = wm;
  const int lane_r = l & 15, g = l >> 4;
  const int aoff = wr*16384 + lane_r*128;
  const int boff = 32768 + wc*8192 + lane_r*128;
  const int s0 = ((0*4 + g) ^ (lane_r & 7)) * 16;
  const int s1 = ((1*4 + g) ^ (lane_r & 7)) * 16;

#define ISSUE_A(BUF, H, XA, KOFF)                                             \
  { gload_lds16(embB + (size_t)XA[0*2+(H)]*256 + (KOFF) + sg16,               \
                smem + (BUF) + 0*16384 + (H)*8192 + wid*1024);                \
    gload_lds16(embB + (size_t)XA[1*2+(H)]*256 + (KOFF) + sg16,               \
                smem + (BUF) + 1*16384 + (H)*8192 + wid*1024); }
#define ISSUE_B(BUF, H, LT)                                                   \
  { const int lt_ = (LT) > 99 ? 99 : (LT);                                    \
    const size_t ko_ = (size_t)(cb100 + lt_) * 128 + (H)*1638400u;            \
    gload_lds16(Wb + brow[0] + ko_,                                           \
                smem + (BUF) + 32768 + 0*16384 + wq*8192 + (H)*4096 + wm*1024); \
    gload_lds16(Wb + brow[1] + ko_,                                           \
                smem + (BUF) + 32768 + 1*16384 + wq*8192 + (H)*4096 + wm*1024); }

#define MM8(AF, BF, IB, JB)                                                   \
  _Pragma("unroll") for (int ii = 0; ii < 4; ++ii)                            \
    _Pragma("unroll") for (int jj = 0; jj < 2; ++jj) {                        \
      acc[(IB)+ii][(JB)+jj] = __builtin_amdgcn_mfma_f32_16x16x32_bf16(        \
          AF[ii][0], BF[jj][0], acc[(IB)+ii][(JB)+jj], 0, 0, 0);              \
      acc[(IB)+ii][(JB)+jj] = __builtin_amdgcn_mfma_f32_16x16x32_bf16(        \
          AF[ii][1], BF[jj][1], acc[(IB)+ii][(JB)+jj], 0, 0, 0);              \
    }

#define RD_AF(DST, CB, H)                                                     \
  _Pragma("unroll") for (int ii = 0; ii < 4; ++ii) {                          \
    DST[ii][0] = *(const bf16x8*)(smem + (CB) + aoff + (H)*8192 + ii*2048 + s0); \
    DST[ii][1] = *(const bf16x8*)(smem + (CB) + aoff + (H)*8192 + ii*2048 + s1); \
  }
#define RD_BF(DST, CB, H)                                                     \
  _Pragma("unroll") for (int jj = 0; jj < 2; ++jj) {                          \
    DST[jj][0] = *(const bf16x8*)(smem + (CB) + boff + (H)*4096 + jj*2048 + s0); \
    DST[jj][1] = *(const bf16x8*)(smem + (CB) + boff + (H)*4096 + jj*2048 + s1); \
  }

#define BARW  __builtin_amdgcn_s_barrier();                                   \
              asm volatile("s_waitcnt lgkmcnt(0)" ::: "memory");

#define TILE(CB, ST1, ST2, ST3, ST4, TAIL4)                                   \
  { RD_AF(af, CB, 0) RD_BF(bf, CB, 0)                                         \
    ST1                                                                       \
    BARW                                                                      \
    __builtin_amdgcn_s_setprio(1); MM8(af, bf, 0, 0)                          \
    __builtin_amdgcn_s_setprio(0);                                            \
    __builtin_amdgcn_s_barrier();                                             \
    RD_BF(bf, CB, 1)                                                          \
    ST2                                                                       \
    BARW                                                                      \
    __builtin_amdgcn_s_setprio(1); MM8(af, bf, 0, 2)                          \
    __builtin_amdgcn_s_setprio(0);                                            \
    __builtin_amdgcn_s_barrier();                                             \
    RD_AF(af, CB, 1) RD_BF(bf, CB, 0)                                         \
    ST3                                                                       \
    BARW                                                                      \
    __builtin_amdgcn_s_setprio(1); MM8(af, bf, 4, 0)                          \
    __builtin_amdgcn_s_setprio(0);                                            \
    __builtin_amdgcn_s_barrier();                                             \
    RD_BF(bf, CB, 1)                                                          \
    ST4                                                                       \
    BARW                                                                      \
    __builtin_amdgcn_s_setprio(1); MM8(af, bf, 4, 2)                          \
    __builtin_amdgcn_s_setprio(0);                                            \
    TAIL4                                                                     \
    __builtin_amdgcn_s_barrier(); }

  f32x4 acc[8][4];
  #pragma unroll
  for (int i = 0; i < 8; ++i)
    #pragma unroll
    for (int j = 0; j < 4; ++j)
      acc[i][j] = (f32x4){0.f, 0.f, 0.f, 0.f};

  bf16x8 af[4][2], bf[2][2];

  // ---- prologue: tile0 (A0,A1,B0,B1)->buf0 + tile1 (A0,B0)->buf1; keep tile1 in flight
  int xcur[4], xnxt[4];
  #pragma unroll
  for (int f = 0; f < 4; ++f) xcur[f] = x[xrow[f] + T0];
  #pragma unroll
  for (int f = 0; f < 4; ++f) xnxt[f] = x[xrow[f] + T0 + 1];
  ISSUE_A(0, 0, xcur, 0)
  ISSUE_A(0, 1, xcur, 0)
  ISSUE_B(0, 0, 0)
  ISSUE_B(0, 1, 0)
  ISSUE_A(65536, 0, xcur, 128)
  ISSUE_B(65536, 0, 1)
  asm volatile("s_waitcnt vmcnt(4)" ::: "memory");
  __builtin_amdgcn_s_barrier();

  for (int j = 0; j < 50; ++j) {
    int tnew = T0 + j + 2; if (tnew > CONTENT - 1) tnew = CONTENT - 1;
    int xnew[4];
    #pragma unroll
    for (int f = 0; f < 4; ++f) xnew[f] = x[xrow[f] + tnew];

    // even tile 2j in buf0; stage slots p0-p3
    TILE(0,
         { ISSUE_A(65536, 1, xcur, 128); },
         { ISSUE_B(65536, 1, 2*j+1); },
         { ISSUE_A(0, 0, xnxt, 0); },
         { ISSUE_B(0, 0, 2*j+2); },
         { asm volatile("s_waitcnt vmcnt(4)" ::: "memory"); })
    // odd tile 2j+1 in buf1; stage slots p4-p7
    TILE(65536,
         { ISSUE_A(0, 1, xnxt, 0); },
         { ISSUE_B(0, 1, 2*j+2); },
         { ISSUE_A(65536, 0, xnxt, 128); },
         { ISSUE_B(65536, 0, 2*j+3); },
         { asm volatile("s_waitcnt vmcnt(4)" ::: "memory"); })

    #pragma unroll
    for (int f = 0; f < 4; ++f) { xcur[f] = xnxt[f]; xnxt[f] = xnew[f]; }
  }
#undef TILE
#undef BARW
#undef RD_AF
#undef RD_BF
#undef MM8
#undef ISSUE_A
#undef ISSUE_B

  asm volatile("s_waitcnt vmcnt(0)" ::: "memory");

  // ---- partial store: C/D layout col = lane&15, row = (lane>>4)*4 + reg [HW-verified]
  float* hout = hp + (size_t)chunk * HP_STRIDE;
  const int colBase = n0 + wc * 64 + lane_r;
  const int rowBase = m0 + wr * 128 + (l >> 4) * 4;
  #pragma unroll
  for (int i = 0; i < 8; ++i)
    #pragma unroll
    for (int jj = 0; jj < 4; ++jj)
      #pragma unroll
      for (int r = 0; r < 4; ++r)
        hout[(size_t)(rowBase + i * 16 + r) * HIDDEN + colBase + jj * 16] = acc[i][jj][r];
}

// ---------------- Kernel 3: sum partials + bias + relu + layer2 + softmax ----------------
__global__ __launch_bounds__(256) void k_final(const float* __restrict__ hp,
                                               const float* __restrict__ b1,
                                               const float* __restrict__ w2,
                                               const float* __restrict__ b2,
                                               float* __restrict__ out) {
  const int tid = threadIdx.x;
  const int w = tid >> 6, l = tid & 63;
  const int m = blockIdx.x * 4 + w;     // one wave per batch row
  const float* r0 = hp + (size_t)m * HIDDEN;
  const float* r1 = r0 + HP_STRIDE;
  const float* r2 = r1 + HP_STRIDE;
  const float* r3 = r2 + HP_STRIDE;
  float l0 = 0.f, l1 = 0.f;
  #pragma unroll
  for (int t = 0; t < 4; ++t) {
    int j = t * 256 + l * 4;
    float4 p0 = *(const float4*)(r0 + j);
    float4 p1 = *(const float4*)(r1 + j);
    float4 p2 = *(const float4*)(r2 + j);
    float4 p3 = *(const float4*)(r3 + j);
    float4 bb = *(const float4*)(b1 + j);
    float4 wa = *(const float4*)(w2 + j);
    float4 wb = *(const float4*)(w2 + HIDDEN + j);
    float h;
    h = p0.x + p1.x + p2.x + p3.x + bb.x; h = fmaxf(h, 0.f); l0 += h * wa.x; l1 += h * wb.x;
    h = p0.y + p1.y + p2.y + p3.y + bb.y; h = fmaxf(h, 0.f); l0 += h * wa.y; l1 += h * wb.y;
    h = p0.z + p1.z + p2.z + p3.z + bb.z; h = fmaxf(h, 0.f); l0 += h * wa.z; l1 += h * wb.z;
    h = p0.w + p1.w + p2.w + p3.w + bb.w; h = fmaxf(h, 0.f); l0 += h * wa.w; l1 += h * wb.w;
  }
  #pragma unroll
  for (int off = 32; off > 0; off >>= 1) {
    l0 += __shfl_xor(l0, off, 64);
    l1 += __shfl_xor(l1, off, 64);
  }
  if (l == 0) {
    float z0 = l0 + b2[0], z1 = l1 + b2[1];
    float mx = fmaxf(z0, z1);
    float e0 = expf(z0 - mx), e1 = expf(z1 - mx);
    float s = 1.f / (e0 + e1);
    out[2 * m]     = e0 * s;
    out[2 * m + 1] = e1 * s;
  }
}

extern "C" void kernel_launch(void* const* d_in, const int* in_sizes, int n_in,
                              void* d_out, int out_size, void* d_ws, size_t ws_size,
                              hipStream_t stream) {
  (void)in_sizes; (void)n_in; (void)out_size; (void)ws_size;
  const int*   x   = (const int*)d_in[0];
  const float* emb = (const float*)d_in[1];
  const float* w1  = (const float*)d_in[2];
  const float* b1  = (const float*)d_in[3];
  const float* w2  = (const float*)d_in[4];
  const float* b2  = (const float*)d_in[5];
  float* out = (float*)d_out;
  char* ws = (char*)d_ws;
  bf16_t* embT = (bf16_t*)(ws + WS_EMBT);
  bf16_t* Wbf  = (bf16_t*)(ws + WS_W1);
  float*  hp   = (float*)(ws + WS_HP);

  hipLaunchKernelGGL(k_prep,  dim3(2048), dim3(256), 0, stream, emb, w1, embT, Wbf);
  hipLaunchKernelGGL(k_gemm,  dim3(256), dim3(512), 0, stream, x, embT, Wbf, hp);
  hipLaunchKernelGGL(k_final, dim3(BATCH/4), dim3(256), 0, stream, hp, b1, w2, b2, out);
}